// Round 1
// 242.280 us; speedup vs baseline: 1.0766x; 1.0766x over previous
//
#include <hip/hip_runtime.h>
#include <cstdint>
#include <cstddef>

#define N_NODES 50000
#define N_EDGES 800000
#define INC 128
#define HID 32
#define HEADS 8
#define OUTC 64
#define F1 (HEADS * HID) /* 256 */
#define NEG 0.2f
#define CAP 64  /* bucket capacity; deg ~ Poisson(16), P(any of 50k nodes >= 64) < 1e-14 */

typedef unsigned short bf16_t;
typedef __attribute__((ext_vector_type(8))) short bf16x8;   // MFMA A/B frag (4 VGPR)
typedef __attribute__((ext_vector_type(4))) float f32x4;    // MFMA C/D frag

__device__ __forceinline__ float bf2f(bf16_t u) {
  union { unsigned int i; float f; } v;
  v.i = ((unsigned int)u) << 16;
  return v.f;
}
__device__ __forceinline__ bf16_t f2bf(float x) {
  union { float f; unsigned int u; } v;
  v.f = x;
  unsigned int r = v.u + 0x7FFFu + ((v.u >> 16) & 1u);  // RNE
  return (bf16_t)(r >> 16);
}
__device__ __forceinline__ float lrexp(float v) {
  return expf((v >= 0.f) ? v : NEG * v);
}

// ---------------------------------------------------------------------------
// prep: replaces the cnt memset dispatch. Zeroes cnt AND pre-transposes both
// weight matrices to bf16 row-major-over-N layout (Wt[n][k] = bf16(W[k][n])).
// W1T = 64 KB, W2T = 32 KB -> L2-resident for the GEMMs. Reads coalesced
// (consecutive n), writes scattered (fire-and-forget).
// ---------------------------------------------------------------------------
__global__ __launch_bounds__(256) void prep(
    const float* __restrict__ W1, const float* __restrict__ W2,
    bf16_t* __restrict__ W1T, bf16_t* __restrict__ W2T, int* __restrict__ cnt) {
  int t = blockIdx.x * 256 + threadIdx.x;
  if (t < N_NODES) cnt[t] = 0;
  if (t < INC * F1) {               // W1: [128][256] -> W1T: [256][128]
    int k = t >> 8, n = t & 255;    // coalesced read over n
    W1T[(size_t)n * INC + k] = f2bf(W1[t]);
  }
  if (t < F1 * OUTC) {              // W2: [256][64] -> W2T: [64][256]
    int k = t >> 6, n = t & 63;
    W2T[(size_t)n * F1 + k] = f2bf(W2[t]);
  }
}

// ---------------------------------------------------------------------------
// MFMA bf16 GEMM + fused alpha epilogue + (layer1) fused BUCKET FILL.
// B panel (pre-transposed bf16 Wt, 32-64 KB, L2-resident) is loaded DIRECTLY
// global->registers per wave (no LDS staging, no inline transpose/convert).
// A tile staged in LDS with XOR swizzle as before. C stored via LDS ct tile
// with coalesced uint4 stores.
// ---------------------------------------------------------------------------
template <bool AF32, int HPT, int HTOT>
__global__ __launch_bounds__(256) void mfma_gemm_fused(
    const void* __restrict__ Av, const bf16_t* __restrict__ Wt,
    bf16_t* __restrict__ C, const float* __restrict__ a_src,
    const float* __restrict__ a_dst, float* __restrict__ as,
    float* __restrict__ ad, int M, int N, int K,
    const int* __restrict__ srcE, const int* __restrict__ dstE,
    int* __restrict__ cnt, int* __restrict__ bucket) {
  constexpr int BM = 64, BN = 64, BK = 64;
  __shared__ union SM {
    bf16_t A[BM * BK];                                   // 8 KB (k-loop)
    struct { float ct[64][65]; float pr[64][4]; } epi;   // 17.6 KB (epilogue)
  } sm;

  const int tid = threadIdx.x;

  // fused bucket fill (layer-1 only): 800,768-thread grid covers 800k edges
  if (cnt != nullptr) {
    int eid = (blockIdx.y * gridDim.x + blockIdx.x) * 256 + tid;
    if (eid < N_EDGES) {
      int dd = dstE[eid];
      int pos = atomicAdd(&cnt[dd], 1);
      bucket[(size_t)dd * CAP + pos] = srcE[eid];
    }
  }

  const int wave = tid >> 6, lane = tid & 63;
  const int wm = (wave >> 1) * 32, wn = (wave & 1) * 32;
  const int lr = lane & 15, lq = lane >> 4;
  const int m0 = blockIdx.y * BM, n0 = blockIdx.x * BN;
  const float* A32 = (const float*)Av;
  const bf16_t* A16 = (const bf16_t*)Av;

  f32x4 acc[2][2] = {};

  for (int k0 = 0; k0 < K; k0 += BK) {
    // B fragments: direct global->reg from L2-resident Wt[n][k].
    // Issued first so latency hides under A staging + barrier.
    bf16x8 bcur[2][2];  // [kk][ni]
#pragma unroll
    for (int ni = 0; ni < 2; ni++) {
      const size_t brow = (size_t)(n0 + wn + ni * 16 + lr) * K;
#pragma unroll
      for (int kk = 0; kk < 2; kk++)
        bcur[kk][ni] = *reinterpret_cast<const bf16x8*>(
            &Wt[brow + k0 + kk * 32 + lq * 8]);
    }

    // A tile staging (XOR-swizzled LDS)
#pragma unroll
    for (int p = 0; p < 2; p++) {
      int id = p * 256 + tid;
      int r = id >> 3, c = id & 7;
      int gm = m0 + r;
      uint4 v = make_uint4(0, 0, 0, 0);
      if constexpr (AF32) {
        if (gm < M) {
          const float4* ap =
              reinterpret_cast<const float4*>(&A32[(size_t)gm * K + k0 + c * 8]);
          float4 v0 = ap[0], v1 = ap[1];
          union { bf16_t h[8]; uint4 u; } pk;
          pk.h[0] = f2bf(v0.x); pk.h[1] = f2bf(v0.y);
          pk.h[2] = f2bf(v0.z); pk.h[3] = f2bf(v0.w);
          pk.h[4] = f2bf(v1.x); pk.h[5] = f2bf(v1.y);
          pk.h[6] = f2bf(v1.z); pk.h[7] = f2bf(v1.w);
          v = pk.u;
        }
      } else {
        if (gm < M) v = *reinterpret_cast<const uint4*>(&A16[(size_t)gm * K + k0 + c * 8]);
      }
      *reinterpret_cast<uint4*>(&sm.A[r * BK + ((c ^ (r & 7)) * 8)]) = v;
    }
    __syncthreads();
#pragma unroll
    for (int kk = 0; kk < 2; kk++) {
      bf16x8 af[2];
#pragma unroll
      for (int mi = 0; mi < 2; mi++) {
        int rr = wm + mi * 16 + lr;
        af[mi] = *reinterpret_cast<const bf16x8*>(
            &sm.A[rr * BK + (((kk * 4 + lq) ^ (rr & 7)) * 8)]);
      }
#pragma unroll
      for (int mi = 0; mi < 2; mi++)
#pragma unroll
        for (int ni = 0; ni < 2; ni++)
          acc[mi][ni] = __builtin_amdgcn_mfma_f32_16x16x32_bf16(
              af[mi], bcur[kk][ni], acc[mi][ni], 0, 0, 0);
    }
    __syncthreads();
  }

  // stage C tile (fp32) to LDS for alpha dots + vectorized C store
#pragma unroll
  for (int mi = 0; mi < 2; mi++)
#pragma unroll
    for (int ni = 0; ni < 2; ni++)
#pragma unroll
      for (int r = 0; r < 4; r++)
        sm.epi.ct[wm + mi * 16 + lq * 4 + r][wn + ni * 16 + lr] = acc[mi][ni][r];
  __syncthreads();

  // global C stores (bf16): coalesced uint4 from LDS tile.
  // thread -> (row = tid>>2, 16-col chunk = tid&3); wave covers 16 rows x 128B.
  {
    int row = tid >> 2, ch = tid & 3;
    int gm = m0 + row;
    if (gm < M) {
      union { bf16_t h[8]; uint4 u; } pk0, pk1;
#pragma unroll
      for (int c = 0; c < 8; c++) pk0.h[c] = f2bf(sm.epi.ct[row][ch * 16 + c]);
#pragma unroll
      for (int c = 0; c < 8; c++) pk1.h[c] = f2bf(sm.epi.ct[row][ch * 16 + 8 + c]);
      *reinterpret_cast<uint4*>(&C[(size_t)gm * N + n0 + ch * 16]) = pk0.u;
      *reinterpret_cast<uint4*>(&C[(size_t)gm * N + n0 + ch * 16 + 8]) = pk1.u;
    }
  }

  // alpha: 64 rows x 4 parts; part&1 = column half, part&2 = src/dst
  {
    int row = tid >> 2, part = tid & 3;
    int gn = m0 + row;
    const float* av = ((part & 2) ? a_dst : a_src) + n0 + (part & 1) * 32;
    float dot = 0.f;
#pragma unroll
    for (int c = 0; c < 32; c++) dot += sm.epi.ct[row][(part & 1) * 32 + c] * av[c];
    if constexpr (HPT == 2) {
      if (gn < M) {
        float* tgt = (part & 2) ? ad : as;
        tgt[(size_t)gn * HTOT + (n0 >> 5) + (part & 1)] = dot;
      }
    } else {
      sm.epi.pr[row][part] = dot;
      __syncthreads();
      if (part == 0 && gn < M) {
        as[gn] = sm.epi.pr[row][0] + sm.epi.pr[row][1];
        ad[gn] = sm.epi.pr[row][2] + sm.epi.pr[row][3];
      }
    }
  }
}

// ---------------------------------------------------------------------------
// Fused score+aggregate, layer 1 (bucket-indexed). Wave per node, 8
// edges/chunk; SGPR-base gathers (readlane); next chunk's indices+scores
// prefetched while gathers in flight; z in score layout + shfl_xor reduction.
// ---------------------------------------------------------------------------
__global__ __launch_bounds__(256) void gat_aggr1(
    const int* __restrict__ cnt, const int* __restrict__ bucket,
    const float* __restrict__ as, const float* __restrict__ ad,
    const bf16_t* __restrict__ hb, const float* __restrict__ bias,
    bf16_t* __restrict__ outp) {
  int d = blockIdx.x * 4 + (threadIdx.x >> 6);
  int lane = threadIdx.x & 63;
  if (d >= N_NODES) return;
  int deg = cnt[d];
  const int* bkt = bucket + (size_t)d * CAP;
  const int sh = lane & 7;   // scorer head
  const int es = lane >> 3;  // scorer edge slot 0..7
  const int ah = lane >> 3;  // aggregation head for feats 4*lane..4*lane+3
  float ad_h = ad[(size_t)d * 8 + sh];
  float a0 = 0.f, a1 = 0.f, a2 = 0.f, a3 = 0.f, zacc = 0.f;

  if (deg > 0) {
    int ei = es;
    int s_reg = bkt[(ei < deg) ? ei : deg - 1];
    float w_reg = (ei < deg) ? lrexp(as[(size_t)s_reg * 8 + sh] + ad_h) : 0.f;

    for (int cb = 0; cb < deg; cb += 8) {
      // SGPR base pointers for current chunk's 8 gathers (d wave-uniform)
      const bf16_t* bs[8];
#pragma unroll
      for (int e = 0; e < 8; e++)
        bs[e] = hb + (size_t)__builtin_amdgcn_readlane(s_reg, e << 3) * F1;
      uint2 g[8];
#pragma unroll
      for (int e = 0; e < 8; e++)
        g[e] = *reinterpret_cast<const uint2*>(bs[e] + 4 * lane);
      float w_cur = w_reg;
      zacc += w_reg;  // score-layout z: one add per chunk
      // prefetch next chunk's indices + scores while gathers are in flight
      int nxt = cb + 8;
      if (nxt < deg) {
        int ei2 = nxt + es;
        s_reg = bkt[(ei2 < deg) ? ei2 : deg - 1];
        w_reg = (ei2 < deg) ? lrexp(as[(size_t)s_reg * 8 + sh] + ad_h) : 0.f;
      }
      // FMA current chunk
#pragma unroll
      for (int e = 0; e < 8; e++) {
        float wv = __shfl(w_cur, (e << 3) | ah);
        union { uint2 u; bf16_t h[4]; } ld;
        ld.u = g[e];
        a0 += bf2f(ld.h[0]) * wv;
        a1 += bf2f(ld.h[1]) * wv;
        a2 += bf2f(ld.h[2]) * wv;
        a3 += bf2f(ld.h[3]) * wv;
      }
    }
  }

  // z reduction over edge-slot bits (lane bits 3..5), fetch for head ah
  float zr = zacc;
  zr += __shfl_xor(zr, 8);
  zr += __shfl_xor(zr, 16);
  zr += __shfl_xor(zr, 32);
  float z = __shfl(zr, ah);

  float inv = (deg > 0) ? (1.f / z) : 0.f;
  float4 bv = *reinterpret_cast<const float4*>(&bias[4 * lane]);
  float v0 = a0 * inv + bv.x;
  float v1 = a1 * inv + bv.y;
  float v2 = a2 * inv + bv.z;
  float v3 = a3 * inv + bv.w;
  v0 = (v0 > 0.f) ? v0 : expm1f(v0);
  v1 = (v1 > 0.f) ? v1 : expm1f(v1);
  v2 = (v2 > 0.f) ? v2 : expm1f(v2);
  v3 = (v3 > 0.f) ? v3 : expm1f(v3);
  union { bf16_t h[4]; uint2 u; } pk;
  pk.h[0] = f2bf(v0); pk.h[1] = f2bf(v1); pk.h[2] = f2bf(v2); pk.h[3] = f2bf(v3);
  *reinterpret_cast<uint2*>(&outp[(size_t)d * F1 + 4 * lane]) = pk.u;
}

// ---------------------------------------------------------------------------
// Fused score+aggregate, layer 2 (H=1, C=64). Eight lanes per dst node, lane
// owns 8 feats (uint4), 8 nodes/wave, pipelined scores; z via width-8 xor.
// ---------------------------------------------------------------------------
__global__ __launch_bounds__(256) void gat_aggr2(
    const int* __restrict__ cnt, const int* __restrict__ bucket,
    const float* __restrict__ as, const float* __restrict__ ad,
    const bf16_t* __restrict__ hb, const float* __restrict__ bias,
    float* __restrict__ outp) {
  int d = blockIdx.x * 32 + (threadIdx.x >> 3);
  int sub = threadIdx.x & 7;
  if (d >= N_NODES) return;
  int deg = cnt[d];
  const int* bkt = bucket + (size_t)d * CAP;
  float ad_d = ad[d];
  float acc[8] = {};
  float zacc = 0.f;

  if (deg > 0) {
    int ei = sub;
    int s_reg = bkt[(ei < deg) ? ei : deg - 1];
    float w_reg = (ei < deg) ? lrexp(as[s_reg] + ad_d) : 0.f;

    for (int cb = 0; cb < deg; cb += 8) {
      int sv[8];
#pragma unroll
      for (int e = 0; e < 8; e++) sv[e] = __shfl(s_reg, e, 8);
      uint4 g[8];
#pragma unroll
      for (int e = 0; e < 8; e++)
        g[e] = *reinterpret_cast<const uint4*>(&hb[(size_t)sv[e] * OUTC + 8 * sub]);
      float w_cur = w_reg;
      zacc += w_reg;
      int nxt = cb + 8;
      if (nxt < deg) {
        int ei2 = nxt + sub;
        s_reg = bkt[(ei2 < deg) ? ei2 : deg - 1];
        w_reg = (ei2 < deg) ? lrexp(as[s_reg] + ad_d) : 0.f;
      }
#pragma unroll
      for (int e = 0; e < 8; e++) {
        float wv = __shfl(w_cur, e, 8);
        union { uint4 u; bf16_t h[8]; } ld;
        ld.u = g[e];
#pragma unroll
        for (int q = 0; q < 8; q++) acc[q] += bf2f(ld.h[q]) * wv;
      }
    }
  }

  float zr = zacc;
  zr += __shfl_xor(zr, 1, 8);
  zr += __shfl_xor(zr, 2, 8);
  zr += __shfl_xor(zr, 4, 8);

  float inv = (deg > 0) ? (1.f / zr) : 0.f;
  float4 o0, o1;
  o0.x = acc[0] * inv + bias[8 * sub + 0];
  o0.y = acc[1] * inv + bias[8 * sub + 1];
  o0.z = acc[2] * inv + bias[8 * sub + 2];
  o0.w = acc[3] * inv + bias[8 * sub + 3];
  o1.x = acc[4] * inv + bias[8 * sub + 4];
  o1.y = acc[5] * inv + bias[8 * sub + 5];
  o1.z = acc[6] * inv + bias[8 * sub + 6];
  o1.w = acc[7] * inv + bias[8 * sub + 7];
  *reinterpret_cast<float4*>(&outp[(size_t)d * OUTC + 8 * sub]) = o0;
  *reinterpret_cast<float4*>(&outp[(size_t)d * OUTC + 8 * sub + 4]) = o1;
}

extern "C" void kernel_launch(void* const* d_in, const int* in_sizes, int n_in,
                              void* d_out, int out_size, void* d_ws, size_t ws_size,
                              hipStream_t stream) {
  const float* x      = (const float*)d_in[0];
  const int*   ei     = (const int*)d_in[1];
  const float* W1     = (const float*)d_in[2];
  const float* a1_src = (const float*)d_in[3];
  const float* a1_dst = (const float*)d_in[4];
  const float* b1     = (const float*)d_in[5];
  const float* W2     = (const float*)d_in[6];
  const float* a2_src = (const float*)d_in[7];
  const float* a2_dst = (const float*)d_in[8];
  const float* b2     = (const float*)d_in[9];

  const int* src = ei;
  const int* dst = ei + N_EDGES;
  float* out = (float*)d_out;

  char* base = (char*)d_ws;
  size_t off = 0;
  auto carve = [&](size_t bytes) {
    void* q = base + off;
    off += (bytes + 255) & ~size_t(255);
    return q;
  };
  bf16_t* h1b  = (bf16_t*)carve((size_t)N_NODES * F1 * 2);     // 25.6 MB
  bf16_t* o1b  = (bf16_t*)carve((size_t)N_NODES * F1 * 2);     // 25.6 MB
  bf16_t* h2b  = (bf16_t*)carve((size_t)N_NODES * OUTC * 2);   // 6.4 MB
  float* as1 = (float*)carve((size_t)N_NODES * HEADS * 4);
  float* ad1 = (float*)carve((size_t)N_NODES * HEADS * 4);
  float* as2 = (float*)carve((size_t)N_NODES * 4);
  float* ad2 = (float*)carve((size_t)N_NODES * 4);
  int* cnt = (int*)carve((size_t)N_NODES * 4);
  int* bucket = (int*)carve((size_t)N_NODES * CAP * 4);        // 12.8 MB
  bf16_t* w1t = (bf16_t*)carve((size_t)F1 * INC * 2);          // 64 KB
  bf16_t* w2t = (bf16_t*)carve((size_t)OUTC * F1 * 2);         // 32 KB

  // ---- 0. prep: cnt=0 + W1T/W2T bf16 pre-transpose (replaces memset) ----
  prep<<<(N_NODES + 255) / 256, 256, 0, stream>>>(W1, W2, w1t, w2t, cnt);

  // ---- 1. layer 1 GEMM (+ fused bucket fill, reg-resident B) ----
  mfma_gemm_fused<true, 2, HEADS><<<dim3(F1 / 64, (N_NODES + 63) / 64), 256, 0, stream>>>(
      x, w1t, h1b, a1_src, a1_dst, as1, ad1, N_NODES, F1, INC, src, dst, cnt, bucket);

  // ---- 2. layer 1 aggregation ----
  gat_aggr1<<<(N_NODES + 3) / 4, 256, 0, stream>>>(cnt, bucket, as1, ad1, h1b, b1, o1b);

  // ---- 3. layer 2 GEMM (reg-resident B, fused alpha) ----
  mfma_gemm_fused<false, 1, 1><<<dim3(OUTC / 64, (N_NODES + 63) / 64), 256, 0, stream>>>(
      o1b, w2t, h2b, a2_src, a2_dst, as2, ad2, N_NODES, OUTC, F1,
      nullptr, nullptr, nullptr, nullptr);

  // ---- 4. layer 2 aggregation ----
  gat_aggr2<<<(N_NODES + 31) / 32, 256, 0, stream>>>(cnt, bucket, as2, ad2, h2b, b2, out);
}

// Round 2
// 240.656 us; speedup vs baseline: 1.0839x; 1.0068x over previous
//
#include <hip/hip_runtime.h>
#include <cstdint>
#include <cstddef>

#define N_NODES 50000
#define N_EDGES 800000
#define INC 128
#define HID 32
#define HEADS 8
#define OUTC 64
#define F1 (HEADS * HID) /* 256 */
#define NEG 0.2f
#define CAP 64  /* bucket capacity; deg ~ Poisson(16), P(any of 50k nodes >= 64) < 1e-14 */

typedef unsigned short bf16_t;
typedef unsigned short u16;
typedef __attribute__((ext_vector_type(8))) short bf16x8;   // MFMA A/B frag (4 VGPR)
typedef __attribute__((ext_vector_type(4))) float f32x4;    // MFMA C/D frag

__device__ __forceinline__ float bf2f(bf16_t u) {
  union { unsigned int i; float f; } v;
  v.i = ((unsigned int)u) << 16;
  return v.f;
}
__device__ __forceinline__ bf16_t f2bf(float x) {
  union { float f; unsigned int u; } v;
  v.f = x;
  unsigned int r = v.u + 0x7FFFu + ((v.u >> 16) & 1u);  // RNE
  return (bf16_t)(r >> 16);
}
__device__ __forceinline__ float lrexp(float v) {
  return expf((v >= 0.f) ? v : NEG * v);
}

// ---------------------------------------------------------------------------
// prep: zero cnt; bf16 pre-transpose both weights (L2-resident for GEMMs);
// bf16 pre-convert x (halves gemm1's A fetch + removes f2bf from staging).
// 3125 blocks x 256 = 800k threads; x-convert 8 elems/thread, streaming.
// ---------------------------------------------------------------------------
__global__ __launch_bounds__(256) void prep(
    const float* __restrict__ x, const float* __restrict__ W1,
    const float* __restrict__ W2, bf16_t* __restrict__ xb,
    bf16_t* __restrict__ W1T, bf16_t* __restrict__ W2T, int* __restrict__ cnt) {
  int t = blockIdx.x * 256 + threadIdx.x;
  if (t < (N_NODES * INC) / 8) {
    const float4* xp = reinterpret_cast<const float4*>(x + (size_t)t * 8);
    float4 v0 = xp[0], v1 = xp[1];
    union { bf16_t h[8]; uint4 u; } pk;
    pk.h[0] = f2bf(v0.x); pk.h[1] = f2bf(v0.y);
    pk.h[2] = f2bf(v0.z); pk.h[3] = f2bf(v0.w);
    pk.h[4] = f2bf(v1.x); pk.h[5] = f2bf(v1.y);
    pk.h[6] = f2bf(v1.z); pk.h[7] = f2bf(v1.w);
    *reinterpret_cast<uint4*>(xb + (size_t)t * 8) = pk.u;
  }
  if (t < N_NODES) cnt[t] = 0;
  if (t < INC * F1) {               // W1: [128][256] -> W1T: [256][128]
    int k = t >> 8, n = t & 255;    // coalesced read over n
    W1T[(size_t)n * INC + k] = f2bf(W1[t]);
  }
  if (t < F1 * OUTC) {              // W2: [256][64] -> W2T: [64][256]
    int k = t >> 6, n = t & 63;
    W2T[(size_t)n * F1 + k] = f2bf(W2[t]);
  }
}

// ---------------------------------------------------------------------------
// MFMA bf16 GEMM + fused alpha epilogue + (layer1) fused BUCKET FILL.
// Persistent grid (<=2048 blocks) with tile loop (kills tail taper).
// A is pre-converted bf16; staging is pure uint4 copy with XOR swizzle.
// Register prefetch: both K-halves' A and B global loads issued before the
// first barrier of the pair, so K-step 2 never waits on global latency.
// B loaded direct global->reg from L2-resident Wt (no LDS staging).
// Bucket entries are u16 (src < 65536): halves scatter write-allocate traffic.
// ---------------------------------------------------------------------------
template <int HPT, int HTOT>
__global__ __launch_bounds__(256) void mfma_gemm_fused(
    const bf16_t* __restrict__ A16, const bf16_t* __restrict__ Wt,
    bf16_t* __restrict__ C, const float* __restrict__ a_src,
    const float* __restrict__ a_dst, float* __restrict__ as,
    float* __restrict__ ad, int M, int N, int K, int numTiles,
    const int* __restrict__ srcE, const int* __restrict__ dstE,
    int* __restrict__ cnt, u16* __restrict__ bucket) {
  constexpr int BM = 64, BN = 64, BK = 64;
  __shared__ union SM {
    bf16_t A[BM * BK];                                   // 8 KB (k-loop)
    struct { float ct[64][65]; float pr[64][4]; } epi;   // 17.6 KB (epilogue)
  } sm;

  const int tid = threadIdx.x;
  const int wave = tid >> 6, lane = tid & 63;
  const int wm = (wave >> 1) * 32, wn = (wave & 1) * 32;
  const int lr = lane & 15, lq = lane >> 4;
  const int r0 = tid >> 3, c0 = tid & 7;   // staging slot p=0 (rows 0..31)
  const int r1 = 32 + r0;                  // staging slot p=1 (rows 32..63)
  const int ntx = N >> 6;                  // tiles along N

  for (int t = blockIdx.x; t < numTiles; t += gridDim.x) {
    // fused bucket fill (layer-1 only); tiles cover 3128*256 >= 800k edges
    if (cnt != nullptr) {
      int eid = t * 256 + tid;
      if (eid < N_EDGES) {
        int dd = dstE[eid];
        int pos = atomicAdd(&cnt[dd], 1);
        bucket[(size_t)dd * CAP + pos] = (u16)srcE[eid];
      }
    }
    const int m0 = (t / ntx) * BM, n0 = (t % ntx) * BN;

    f32x4 acc[2][2] = {};

    auto loadA = [&](int k0, uint4& v0, uint4& v1) {
      int gm0 = m0 + r0, gm1 = m0 + r1;
      v0 = (gm0 < M) ? *reinterpret_cast<const uint4*>(&A16[(size_t)gm0 * K + k0 + c0 * 8])
                     : make_uint4(0, 0, 0, 0);
      v1 = (gm1 < M) ? *reinterpret_cast<const uint4*>(&A16[(size_t)gm1 * K + k0 + c0 * 8])
                     : make_uint4(0, 0, 0, 0);
    };
    auto writeA = [&](const uint4& v0, const uint4& v1) {
      *reinterpret_cast<uint4*>(&sm.A[r0 * BK + ((c0 ^ (r0 & 7)) * 8)]) = v0;
      *reinterpret_cast<uint4*>(&sm.A[r1 * BK + ((c0 ^ (r1 & 7)) * 8)]) = v1;
    };
    auto loadB = [&](int k0, bf16x8 (&b)[2][2]) {
#pragma unroll
      for (int ni = 0; ni < 2; ni++) {
        const size_t brow = (size_t)(n0 + wn + ni * 16 + lr) * K;
#pragma unroll
        for (int kk = 0; kk < 2; kk++)
          b[kk][ni] = *reinterpret_cast<const bf16x8*>(&Wt[brow + k0 + kk * 32 + lq * 8]);
      }
    };
    auto mstep = [&](const bf16x8 (&b)[2][2]) {
#pragma unroll
      for (int kk = 0; kk < 2; kk++) {
        bf16x8 af[2];
#pragma unroll
        for (int mi = 0; mi < 2; mi++) {
          int rr = wm + mi * 16 + lr;
          af[mi] = *reinterpret_cast<const bf16x8*>(
              &sm.A[rr * BK + (((kk * 4 + lq) ^ (rr & 7)) * 8)]);
        }
#pragma unroll
        for (int mi = 0; mi < 2; mi++)
#pragma unroll
          for (int ni = 0; ni < 2; ni++)
            acc[mi][ni] = __builtin_amdgcn_mfma_f32_16x16x32_bf16(
                af[mi], b[kk][ni], acc[mi][ni], 0, 0, 0);
      }
    };

    uint4 pa0, pa1, qa0, qa1;
    bf16x8 b0[2][2], b1[2][2];
    loadA(0, pa0, pa1);
    for (int k0 = 0; k0 < K; k0 += 2 * BK) {   // K is a multiple of 128
      loadB(k0, b0);
      writeA(pa0, pa1);
      loadA(k0 + BK, qa0, qa1);   // prefetch 2nd half A (issued pre-barrier)
      loadB(k0 + BK, b1);         // prefetch 2nd half B
      __syncthreads();
      mstep(b0);
      __syncthreads();
      writeA(qa0, qa1);
      if (k0 + 2 * BK < K) loadA(k0 + 2 * BK, pa0, pa1);  // next iter prefetch
      __syncthreads();
      mstep(b1);
      __syncthreads();
    }

    // stage C tile (fp32) to LDS for alpha dots + vectorized C store
#pragma unroll
    for (int mi = 0; mi < 2; mi++)
#pragma unroll
      for (int ni = 0; ni < 2; ni++)
#pragma unroll
        for (int r = 0; r < 4; r++)
          sm.epi.ct[wm + mi * 16 + lq * 4 + r][wn + ni * 16 + lr] = acc[mi][ni][r];
    __syncthreads();

    // global C stores (bf16): coalesced uint4 from LDS tile
    {
      int row = tid >> 2, ch = tid & 3;
      int gm = m0 + row;
      if (gm < M) {
        union { bf16_t h[8]; uint4 u; } pk0, pk1;
#pragma unroll
        for (int c = 0; c < 8; c++) pk0.h[c] = f2bf(sm.epi.ct[row][ch * 16 + c]);
#pragma unroll
        for (int c = 0; c < 8; c++) pk1.h[c] = f2bf(sm.epi.ct[row][ch * 16 + 8 + c]);
        *reinterpret_cast<uint4*>(&C[(size_t)gm * N + n0 + ch * 16]) = pk0.u;
        *reinterpret_cast<uint4*>(&C[(size_t)gm * N + n0 + ch * 16 + 8]) = pk1.u;
      }
    }

    // alpha: 64 rows x 4 parts; part&1 = column half, part&2 = src/dst
    {
      int row = tid >> 2, part = tid & 3;
      int gn = m0 + row;
      const float* av = ((part & 2) ? a_dst : a_src) + n0 + (part & 1) * 32;
      float dot = 0.f;
#pragma unroll
      for (int c = 0; c < 32; c++) dot += sm.epi.ct[row][(part & 1) * 32 + c] * av[c];
      if constexpr (HPT == 2) {
        if (gn < M) {
          float* tgt = (part & 2) ? ad : as;
          tgt[(size_t)gn * HTOT + (n0 >> 5) + (part & 1)] = dot;
        }
      } else {
        sm.epi.pr[row][part] = dot;
        __syncthreads();
        if (part == 0 && gn < M) {
          as[gn] = sm.epi.pr[row][0] + sm.epi.pr[row][1];
          ad[gn] = sm.epi.pr[row][2] + sm.epi.pr[row][3];
        }
      }
    }
    __syncthreads();  // epilogue LDS reads done before next tile's staging
  }
}

// ---------------------------------------------------------------------------
// Fused score+aggregate, layer 1 (bucket-indexed, u16 entries). Wave per
// node, 8 edges/chunk; SGPR-base gathers (readlane); next chunk's
// indices+scores prefetched while gathers in flight; z in score layout.
// ---------------------------------------------------------------------------
__global__ __launch_bounds__(256) void gat_aggr1(
    const int* __restrict__ cnt, const u16* __restrict__ bucket,
    const float* __restrict__ as, const float* __restrict__ ad,
    const bf16_t* __restrict__ hb, const float* __restrict__ bias,
    bf16_t* __restrict__ outp) {
  int d = blockIdx.x * 4 + (threadIdx.x >> 6);
  int lane = threadIdx.x & 63;
  if (d >= N_NODES) return;
  int deg = cnt[d];
  const u16* bkt = bucket + (size_t)d * CAP;
  const int sh = lane & 7;   // scorer head
  const int es = lane >> 3;  // scorer edge slot 0..7
  const int ah = lane >> 3;  // aggregation head for feats 4*lane..4*lane+3
  float ad_h = ad[(size_t)d * 8 + sh];
  float a0 = 0.f, a1 = 0.f, a2 = 0.f, a3 = 0.f, zacc = 0.f;

  if (deg > 0) {
    int ei = es;
    int s_reg = (int)bkt[(ei < deg) ? ei : deg - 1];
    float w_reg = (ei < deg) ? lrexp(as[(size_t)s_reg * 8 + sh] + ad_h) : 0.f;

    for (int cb = 0; cb < deg; cb += 8) {
      // SGPR base pointers for current chunk's 8 gathers (d wave-uniform)
      const bf16_t* bs[8];
#pragma unroll
      for (int e = 0; e < 8; e++)
        bs[e] = hb + (size_t)__builtin_amdgcn_readlane(s_reg, e << 3) * F1;
      uint2 g[8];
#pragma unroll
      for (int e = 0; e < 8; e++)
        g[e] = *reinterpret_cast<const uint2*>(bs[e] + 4 * lane);
      float w_cur = w_reg;
      zacc += w_reg;  // score-layout z: one add per chunk
      // prefetch next chunk's indices + scores while gathers are in flight
      int nxt = cb + 8;
      if (nxt < deg) {
        int ei2 = nxt + es;
        s_reg = (int)bkt[(ei2 < deg) ? ei2 : deg - 1];
        w_reg = (ei2 < deg) ? lrexp(as[(size_t)s_reg * 8 + sh] + ad_h) : 0.f;
      }
      // FMA current chunk
#pragma unroll
      for (int e = 0; e < 8; e++) {
        float wv = __shfl(w_cur, (e << 3) | ah);
        union { uint2 u; bf16_t h[4]; } ld;
        ld.u = g[e];
        a0 += bf2f(ld.h[0]) * wv;
        a1 += bf2f(ld.h[1]) * wv;
        a2 += bf2f(ld.h[2]) * wv;
        a3 += bf2f(ld.h[3]) * wv;
      }
    }
  }

  // z reduction over edge-slot bits (lane bits 3..5), fetch for head ah
  float zr = zacc;
  zr += __shfl_xor(zr, 8);
  zr += __shfl_xor(zr, 16);
  zr += __shfl_xor(zr, 32);
  float z = __shfl(zr, ah);

  float inv = (deg > 0) ? (1.f / z) : 0.f;
  float4 bv = *reinterpret_cast<const float4*>(&bias[4 * lane]);
  float v0 = a0 * inv + bv.x;
  float v1 = a1 * inv + bv.y;
  float v2 = a2 * inv + bv.z;
  float v3 = a3 * inv + bv.w;
  v0 = (v0 > 0.f) ? v0 : expm1f(v0);
  v1 = (v1 > 0.f) ? v1 : expm1f(v1);
  v2 = (v2 > 0.f) ? v2 : expm1f(v2);
  v3 = (v3 > 0.f) ? v3 : expm1f(v3);
  union { bf16_t h[4]; uint2 u; } pk;
  pk.h[0] = f2bf(v0); pk.h[1] = f2bf(v1); pk.h[2] = f2bf(v2); pk.h[3] = f2bf(v3);
  *reinterpret_cast<uint2*>(&outp[(size_t)d * F1 + 4 * lane]) = pk.u;
}

// ---------------------------------------------------------------------------
// Fused score+aggregate, layer 2 (H=1, C=64, u16 bucket). Eight lanes per
// dst node, lane owns 8 feats (uint4), 8 nodes/wave, pipelined scores.
// ---------------------------------------------------------------------------
__global__ __launch_bounds__(256) void gat_aggr2(
    const int* __restrict__ cnt, const u16* __restrict__ bucket,
    const float* __restrict__ as, const float* __restrict__ ad,
    const bf16_t* __restrict__ hb, const float* __restrict__ bias,
    float* __restrict__ outp) {
  int d = blockIdx.x * 32 + (threadIdx.x >> 3);
  int sub = threadIdx.x & 7;
  if (d >= N_NODES) return;
  int deg = cnt[d];
  const u16* bkt = bucket + (size_t)d * CAP;
  float ad_d = ad[d];
  float acc[8] = {};
  float zacc = 0.f;

  if (deg > 0) {
    int ei = sub;
    int s_reg = (int)bkt[(ei < deg) ? ei : deg - 1];
    float w_reg = (ei < deg) ? lrexp(as[s_reg] + ad_d) : 0.f;

    for (int cb = 0; cb < deg; cb += 8) {
      int sv[8];
#pragma unroll
      for (int e = 0; e < 8; e++) sv[e] = __shfl(s_reg, e, 8);
      uint4 g[8];
#pragma unroll
      for (int e = 0; e < 8; e++)
        g[e] = *reinterpret_cast<const uint4*>(&hb[(size_t)sv[e] * OUTC + 8 * sub]);
      float w_cur = w_reg;
      zacc += w_reg;
      int nxt = cb + 8;
      if (nxt < deg) {
        int ei2 = nxt + sub;
        s_reg = (int)bkt[(ei2 < deg) ? ei2 : deg - 1];
        w_reg = (ei2 < deg) ? lrexp(as[s_reg] + ad_d) : 0.f;
      }
#pragma unroll
      for (int e = 0; e < 8; e++) {
        float wv = __shfl(w_cur, e, 8);
        union { uint4 u; bf16_t h[8]; } ld;
        ld.u = g[e];
#pragma unroll
        for (int q = 0; q < 8; q++) acc[q] += bf2f(ld.h[q]) * wv;
      }
    }
  }

  float zr = zacc;
  zr += __shfl_xor(zr, 1, 8);
  zr += __shfl_xor(zr, 2, 8);
  zr += __shfl_xor(zr, 4, 8);

  float inv = (deg > 0) ? (1.f / zr) : 0.f;
  float4 o0, o1;
  o0.x = acc[0] * inv + bias[8 * sub + 0];
  o0.y = acc[1] * inv + bias[8 * sub + 1];
  o0.z = acc[2] * inv + bias[8 * sub + 2];
  o0.w = acc[3] * inv + bias[8 * sub + 3];
  o1.x = acc[4] * inv + bias[8 * sub + 4];
  o1.y = acc[5] * inv + bias[8 * sub + 5];
  o1.z = acc[6] * inv + bias[8 * sub + 6];
  o1.w = acc[7] * inv + bias[8 * sub + 7];
  *reinterpret_cast<float4*>(&outp[(size_t)d * OUTC + 8 * sub]) = o0;
  *reinterpret_cast<float4*>(&outp[(size_t)d * OUTC + 8 * sub + 4]) = o1;
}

extern "C" void kernel_launch(void* const* d_in, const int* in_sizes, int n_in,
                              void* d_out, int out_size, void* d_ws, size_t ws_size,
                              hipStream_t stream) {
  const float* x      = (const float*)d_in[0];
  const int*   ei     = (const int*)d_in[1];
  const float* W1     = (const float*)d_in[2];
  const float* a1_src = (const float*)d_in[3];
  const float* a1_dst = (const float*)d_in[4];
  const float* b1     = (const float*)d_in[5];
  const float* W2     = (const float*)d_in[6];
  const float* a2_src = (const float*)d_in[7];
  const float* a2_dst = (const float*)d_in[8];
  const float* b2     = (const float*)d_in[9];

  const int* src = ei;
  const int* dst = ei + N_EDGES;
  float* out = (float*)d_out;

  char* base = (char*)d_ws;
  size_t off = 0;
  auto carve = [&](size_t bytes) {
    void* q = base + off;
    off += (bytes + 255) & ~size_t(255);
    return q;
  };
  bf16_t* h1b  = (bf16_t*)carve((size_t)N_NODES * F1 * 2);     // 25.6 MB
  bf16_t* o1b  = (bf16_t*)carve((size_t)N_NODES * F1 * 2);     // 25.6 MB
  float* as1 = (float*)carve((size_t)N_NODES * HEADS * 4);
  float* ad1 = (float*)carve((size_t)N_NODES * HEADS * 4);
  float* as2 = (float*)carve((size_t)N_NODES * 4);
  float* ad2 = (float*)carve((size_t)N_NODES * 4);
  int* cnt = (int*)carve((size_t)N_NODES * 4);
  u16* bucket = (u16*)carve((size_t)N_NODES * CAP * 2);        // 6.4 MB
  bf16_t* w1t = (bf16_t*)carve((size_t)F1 * INC * 2);          // 64 KB
  bf16_t* w2t = (bf16_t*)carve((size_t)OUTC * F1 * 2);         // 32 KB
  bf16_t* xb  = (bf16_t*)carve((size_t)N_NODES * INC * 2);     // 12.8 MB
  bf16_t* h2b = h1b;  // h1b dead after aggr1; reuse for layer-2 GEMM output

  // ---- 0. prep: cnt=0 + W1T/W2T transpose + x -> bf16 ----
  prep<<<(N_NODES * INC / 8 + 255) / 256, 256, 0, stream>>>(
      x, W1, W2, xb, w1t, w2t, cnt);

  // ---- 1. layer 1 GEMM (+ fused bucket fill), persistent grid ----
  {
    int numTiles = ((N_NODES + 63) / 64) * (F1 / 64);  // 782*4 = 3128
    int grid = numTiles < 2048 ? numTiles : 2048;
    mfma_gemm_fused<2, HEADS><<<grid, 256, 0, stream>>>(
        xb, w1t, h1b, a1_src, a1_dst, as1, ad1, N_NODES, F1, INC, numTiles,
        src, dst, cnt, bucket);
  }

  // ---- 2. layer 1 aggregation ----
  gat_aggr1<<<(N_NODES + 3) / 4, 256, 0, stream>>>(cnt, bucket, as1, ad1, h1b, b1, o1b);

  // ---- 3. layer 2 GEMM (fused alpha) ----
  {
    int numTiles = ((N_NODES + 63) / 64) * (OUTC / 64);  // 782
    mfma_gemm_fused<1, 1><<<numTiles, 256, 0, stream>>>(
        o1b, w2t, h2b, a2_src, a2_dst, as2, ad2, N_NODES, OUTC, F1, numTiles,
        nullptr, nullptr, nullptr, nullptr);
  }

  // ---- 4. layer 2 aggregation ----
  gat_aggr2<<<(N_NODES + 31) / 32, 256, 0, stream>>>(cnt, bucket, as2, ad2, h2b, b2, out);
}